// Round 2
// baseline (249.914 us; speedup 1.0000x reference)
//
#include <hip/hip_runtime.h>
#include <math.h>

#define NPTS 16384
#define HDIM 64
#define NBINS 32768
#define CAP 32
#define XLO -8.0f
#define INVW 2048.0f            // NBINS / 16
#define BINW (1.0f / INVW)
#define EPSF 1e-8f
#define FMAX3 3.402823466e38f

// Monotone, consistent bin index (clamp covers |x|>8, ~16-sigma impossible).
__device__ __forceinline__ int bin_of(float v) {
    int b = (int)((v - XLO) * INVW);
    return min(max(b, 0), NBINS - 1);
}

// keep-2-smallest insert (m1<=m2). m2 reads OLD m1 -> order matters.
__device__ __forceinline__ void ins2(float& m1, float& m2, float d) {
    m2 = __builtin_amdgcn_fmed3f(d, m1, m2);
    m1 = fminf(d, m1);
}

// K1: slotted scatter — rank from atomicAdd, NO prefix scan needed.
// lambda_max ~3.2 => P(bin > 32) ~ 1e-20: CAP=32 never overflows in practice.
// pos[i] = slot of point i (unique) -> exact self-exclusion later, even for
// bit-equal duplicate values.
__global__ __launch_bounds__(256) void scatter_kernel(
    const float* __restrict__ x, unsigned* __restrict__ cnt,
    float* __restrict__ slots, unsigned* __restrict__ pos) {
    const int i = blockIdx.x * 256 + threadIdx.x;
    const float v = x[i];
    const int b = bin_of(v);
    const unsigned r = atomicAdd(&cnt[b], 1u);
    const unsigned s = ((unsigned)b << 5) + r;
    if (r < CAP) slots[s] = v;
    pos[i] = s;
}

// K2: per-point 2-NN via ring walk over slotted bins (no global sort), fused
// with the proven MLP fwd + analytic d2y/dx2 + reduction/ticket epilogue.
// Bound: points of bin bb lie in [XLO+bb*w, XLO+(bb+1)*w) up to ~ulp misbinning
// (~0.004*w); the full-BINW slack makes the stop condition conservative.
// Distances are the same fabsf(xi-xj) as the reference -> bitwise-exact dens.
// Reference: knn = [EPS, d1+EPS, d2+EPS]; mean+EPS = (d1+d2)/3 + 2*EPS.
__global__ __launch_bounds__(64) void final_kernel(
    const float* __restrict__ x, const float* __restrict__ tg,
    const float* __restrict__ w1, const float* __restrict__ b1,
    const float* __restrict__ w2, const float* __restrict__ b2,
    const unsigned* __restrict__ cnt, const float* __restrict__ slots,
    const unsigned* __restrict__ pos, float* __restrict__ acc,
    float* __restrict__ out) {
    const int t = threadIdx.x;        // block = one wave
    const int i = blockIdx.x * 64 + t;

    const float v = x[i];
    const unsigned self = pos[i];
    const int b = (int)(self >> 5);
    float m1 = FMAX3, m2 = FMAX3;
    {   // own bin (contains self -> skip by slot index)
        const unsigned n = min(cnt[b], (unsigned)CAP);
        const unsigned base = (unsigned)b << 5;
        for (unsigned r = 0; r < n; ++r) {
            const unsigned s = base + r;
            if (s != self) ins2(m1, m2, fabsf(v - slots[s]));
        }
    }
    int kL = b - 1, kR = b + 1;
    for (;;) {
        const bool hasL = (kL >= 0), hasR = (kR < NBINS);
        if (!hasL && !hasR) break;
        const float lbL = hasL ? (v - fmaf((float)(kL + 1), BINW, XLO)) : FMAX3;
        const float lbR = hasR ? (fmaf((float)kR, BINW, XLO) - v) : FMAX3;
        if (fminf(lbL, lbR) - BINW >= m2) break;   // conservative stop
        int bb;
        if (lbL <= lbR) { bb = kL; --kL; } else { bb = kR; ++kR; }
        const unsigned n = min(cnt[bb], (unsigned)CAP);
        const unsigned base = (unsigned)bb << 5;
        for (unsigned r = 0; r < n; ++r)
            ins2(m1, m2, fabsf(v - slots[base + r]));
    }
    const float dens = 1.0f / ((m1 + m2) * (1.0f / 3.0f) + 2.0f * EPSF);

    const float xi = v;               // == x[i]
    float y = b2[0];
    float d2a = 0.0f;
#pragma unroll 8
    for (int j = 0; j < HDIM; ++j) {
        float a1 = w1[j], bb = b1[j], a2 = w2[j];   // uniform -> scalar loads
        float u = fmaf(xi, a1, bb);
        float e = __expf(2.0f * u);
        float r = __builtin_amdgcn_rcpf(e + 1.0f);
        float tt = fmaf(-2.0f, r, 1.0f);            // tanh(u)
        y = fmaf(a2, tt, y);
        float g = 2.0f * tt * fmaf(tt, tt, -1.0f);  // -2 t (1 - t^2)
        d2a = fmaf(a2 * a1 * a1, g, d2a);
    }
    float diff = y - tg[i];
    float rs_mse = diff * diff;
    float rs_d2 = d2a * d2a;
    float rs_dn = dens, rmx = dens;
    for (int o = 32; o > 0; o >>= 1) {
        rs_mse += __shfl_down(rs_mse, o);
        rs_d2 += __shfl_down(rs_d2, o);
        rs_dn += __shfl_down(rs_dn, o);
        rmx = fmaxf(rmx, __shfl_down(rmx, o));
    }
    if (t == 0) {
        atomicAdd(&acc[0], rs_mse);
        atomicAdd(&acc[1], rs_d2);
        atomicAdd(&acc[2], rs_dn);
        atomicMax((unsigned int*)&acc[3], __float_as_uint(rmx));  // dens>0: uint order == float order
        __threadfence();
        unsigned int ticket = atomicAdd((unsigned int*)&acc[4], 1u);
        if (ticket == (NPTS / 64) - 1) {
            float s_mse = atomicAdd(&acc[0], 0.0f);
            float s_d2 = atomicAdd(&acc[1], 0.0f);
            float s_dn = atomicAdd(&acc[2], 0.0f);
            float dmax = __uint_as_float(atomicMax((unsigned int*)&acc[3], 0u));
            float mse = s_mse * (1.0f / NPTS);
            float md2 = s_d2 * (1.0f / NPTS);
            float mean_density = (s_dn * (1.0f / NPTS)) / (dmax + EPSF);
            float penalty = 0.01f * (1.0f + 0.1f * mean_density) * md2;
            out[0] = mse + penalty;
            out[1] = mse;
            out[2] = penalty;
        }
    }
}

extern "C" void kernel_launch(void* const* d_in, const int* in_sizes, int n_in,
                              void* d_out, int out_size, void* d_ws, size_t ws_size,
                              hipStream_t stream) {
    const float* x = (const float*)d_in[0];
    const float* tg = (const float*)d_in[1];
    const float* w1 = (const float*)d_in[2];
    const float* b1 = (const float*)d_in[3];
    const float* w2 = (const float*)d_in[4];
    const float* b2 = (const float*)d_in[5];
    float* out = (float*)d_out;
    float* wsf = (float*)d_ws;

    float* acc = wsf;                                  // [0..7]: sums, max, ticket
    unsigned* cnt = (unsigned*)(wsf + 8);              // 32768 u32 bin counts
    unsigned* pos = cnt + NBINS;                       // 16384 u32 self-slots
    float* slots = (float*)(pos + NPTS);               // 32768*32 f32 (gated by cnt, no zeroing)

    // one memset node zeroes acc + cnt (131 KB)
    hipMemsetAsync(d_ws, 0, (8 + NBINS) * sizeof(float), stream);
    hipLaunchKernelGGL(scatter_kernel, dim3(NPTS / 256), dim3(256), 0, stream,
                       x, cnt, slots, pos);
    hipLaunchKernelGGL(final_kernel, dim3(NPTS / 64), dim3(64), 0, stream,
                       x, tg, w1, b1, w2, b2, cnt, slots, pos, acc, out);
}

// Round 3
// 105.202 us; speedup vs baseline: 2.3756x; 2.3756x over previous
//
#include <hip/hip_runtime.h>
#include <math.h>

#define NPTS 16384
#define HDIM 64
#define NBINS 2048
#define CAPLG 7
#define CAP (1 << CAPLG)          // 128 slots/bin; lambda_center ~51 -> never overflows
#define XLO -8.0f
#define INVW 128.0f               // NBINS / 16
#define BINW 0.0078125f           // 1/128, exact power of two -> exact bin edges
#define SLACK (BINW * 0.0625f)    // misbin error is ~2^-12 bins; 128x margin
#define EPSF 1e-8f
#define FMAX3 3.402823466e38f

// Linear binning: (v-XLO) and *INVW are monotone under rounding, int cast
// monotone, clamp monotone => bin(u) < bin(w) implies u <= w. PROVABLE
// (no transcendental involved). Same fn in both kernels -> consistent.
__device__ __forceinline__ int bin_of(float v) {
    int b = (int)((v - XLO) * INVW);
    return min(max(b, 0), NBINS - 1);
}

// keep-2-smallest insert (m1<=m2). m2 reads OLD m1 -> order matters.
__device__ __forceinline__ void ins2(float& m1, float& m2, float d) {
    m2 = __builtin_amdgcn_fmed3f(d, m1, m2);
    m1 = fminf(d, m1);
}

// K1: slotted scatter — rank via atomicAdd, no prefix scan. pos[i] = unique
// slot of point i -> exact self-exclusion even for bit-equal duplicates.
__global__ __launch_bounds__(256) void scatter_kernel(
    const float* __restrict__ x, unsigned* __restrict__ cnt,
    float* __restrict__ slots, unsigned* __restrict__ pos) {
    const int i = blockIdx.x * 256 + threadIdx.x;
    const float v = x[i];
    const int b = bin_of(v);
    const unsigned r = atomicAdd(&cnt[b], 1u);
    const unsigned s = ((unsigned)b << CAPLG) + r;
    if (r < CAP) slots[s] = v;
    pos[i] = s;
}

// K2: exact 2-NN per point, walk with TWO stop rules per side:
//  (a) count rule: once >=2 values from strictly-farther bins on that side
//      have been scanned, every unscanned value there is dominated (bins are
//      monotone) -> side done. Bounds dense-region walks at ~1 bin/side.
//  (b) distance rule: lb(side) - SLACK >= m2 -> side done (exact bin edges).
//      Bounds sparse/tail/boundary walks at ~m2*INVW bins (no edge runaway).
// Then the proven MLP fwd + analytic d2y/dx2 + reduction/ticket epilogue.
// Reference: knn=[EPS,d1+EPS,d2+EPS]; mean+EPS = (d1+d2)/3 + 2*EPS.
__global__ __launch_bounds__(64) void final_kernel(
    const float* __restrict__ x, const float* __restrict__ tg,
    const float* __restrict__ w1, const float* __restrict__ b1,
    const float* __restrict__ w2, const float* __restrict__ b2,
    const unsigned* __restrict__ cnt, const float* __restrict__ slots,
    const unsigned* __restrict__ pos, float* __restrict__ acc,
    float* __restrict__ out) {
    const int t = threadIdx.x;        // block = one wave
    const int i = blockIdx.x * 64 + t;

    const float v = x[i];
    const unsigned self = pos[i];
    const int b = (int)(self >> CAPLG);
    float m1 = FMAX3, m2 = FMAX3;
    {   // own bin (contains self -> skip by slot index)
        const unsigned n = min(cnt[b], (unsigned)CAP);
        const unsigned base = (unsigned)b << CAPLG;
        for (unsigned r = 0; r < n; ++r) {
            const unsigned s = base + r;
            if (s != self) ins2(m1, m2, fabsf(v - slots[s]));
        }
    }
    int kL = b - 1, kR = b + 1;
    unsigned nL = 0, nR = 0;
    for (;;) {
        // exact edges: k*BINW exact (k<=2048, BINW=2^-7), +XLO exact
        const float lbL = (kL >= 0 && nL < 2u)
            ? (v - fmaf((float)(kL + 1), BINW, XLO)) : FMAX3;
        const float lbR = (kR < NBINS && nR < 2u)
            ? (fmaf((float)kR, BINW, XLO) - v) : FMAX3;
        const bool goL = (lbL - SLACK < m2);
        const bool goR = (lbR - SLACK < m2);
        if (!goL && !goR) break;
        const bool left = goL && (!goR || lbL <= lbR);
        const int bb = left ? kL : kR;
        if (left) --kL; else ++kR;
        const unsigned n = min(cnt[bb], (unsigned)CAP);
        const unsigned base = (unsigned)bb << CAPLG;
        for (unsigned r = 0; r < n; ++r)
            ins2(m1, m2, fabsf(v - slots[base + r]));
        if (left) nL += n; else nR += n;
    }
    const float dens = 1.0f / ((m1 + m2) * (1.0f / 3.0f) + 2.0f * EPSF);

    const float xi = v;               // == x[i]
    float y = b2[0];
    float d2a = 0.0f;
#pragma unroll 8
    for (int j = 0; j < HDIM; ++j) {
        float a1 = w1[j], bb = b1[j], a2 = w2[j];   // uniform -> scalar loads
        float u = fmaf(xi, a1, bb);
        float e = __expf(2.0f * u);
        float r = __builtin_amdgcn_rcpf(e + 1.0f);
        float tt = fmaf(-2.0f, r, 1.0f);            // tanh(u)
        y = fmaf(a2, tt, y);
        float g = 2.0f * tt * fmaf(tt, tt, -1.0f);  // -2 t (1 - t^2)
        d2a = fmaf(a2 * a1 * a1, g, d2a);
    }
    float diff = y - tg[i];
    float rs_mse = diff * diff;
    float rs_d2 = d2a * d2a;
    float rs_dn = dens, rmx = dens;
    for (int o = 32; o > 0; o >>= 1) {
        rs_mse += __shfl_down(rs_mse, o);
        rs_d2 += __shfl_down(rs_d2, o);
        rs_dn += __shfl_down(rs_dn, o);
        rmx = fmaxf(rmx, __shfl_down(rmx, o));
    }
    if (t == 0) {
        atomicAdd(&acc[0], rs_mse);
        atomicAdd(&acc[1], rs_d2);
        atomicAdd(&acc[2], rs_dn);
        atomicMax((unsigned int*)&acc[3], __float_as_uint(rmx));  // dens>0: uint order == float order
        __threadfence();
        unsigned int ticket = atomicAdd((unsigned int*)&acc[4], 1u);
        if (ticket == (NPTS / 64) - 1) {
            float s_mse = atomicAdd(&acc[0], 0.0f);
            float s_d2 = atomicAdd(&acc[1], 0.0f);
            float s_dn = atomicAdd(&acc[2], 0.0f);
            float dmax = __uint_as_float(atomicMax((unsigned int*)&acc[3], 0u));
            float mse = s_mse * (1.0f / NPTS);
            float md2 = s_d2 * (1.0f / NPTS);
            float mean_density = (s_dn * (1.0f / NPTS)) / (dmax + EPSF);
            float penalty = 0.01f * (1.0f + 0.1f * mean_density) * md2;
            out[0] = mse + penalty;
            out[1] = mse;
            out[2] = penalty;
        }
    }
}

extern "C" void kernel_launch(void* const* d_in, const int* in_sizes, int n_in,
                              void* d_out, int out_size, void* d_ws, size_t ws_size,
                              hipStream_t stream) {
    const float* x = (const float*)d_in[0];
    const float* tg = (const float*)d_in[1];
    const float* w1 = (const float*)d_in[2];
    const float* b1 = (const float*)d_in[3];
    const float* w2 = (const float*)d_in[4];
    const float* b2 = (const float*)d_in[5];
    float* out = (float*)d_out;
    float* wsf = (float*)d_ws;

    float* acc = wsf;                                  // [0..4]: sums, max, ticket
    unsigned* cnt = (unsigned*)(wsf + 8);              // 2048 u32 bin counts
    unsigned* pos = cnt + NBINS;                       // 16384 u32 self-slots
    float* slots = (float*)(pos + NPTS);               // 2048*128 f32 (gated by cnt)

    // one memset node zeroes acc + cnt (8.2 KB)
    hipMemsetAsync(d_ws, 0, (8 + NBINS) * sizeof(float), stream);
    hipLaunchKernelGGL(scatter_kernel, dim3(NPTS / 256), dim3(256), 0, stream,
                       x, cnt, slots, pos);
    hipLaunchKernelGGL(final_kernel, dim3(NPTS / 64), dim3(64), 0, stream,
                       x, tg, w1, b1, w2, b2, cnt, slots, pos, acc, out);
}